// Round 4
// baseline (575.931 us; speedup 1.0000x reference)
//
#include <hip/hip_runtime.h>
#include <hip/hip_bf16.h>

// Shapes: B=512, S=128, D=128, HS=256, 4HS=1024, O=1.
// Pipeline (all bf16 MFMA, f32 accum):
//   prepw: WaT/VaT/WT transposed bf16 weights + U_eff packed into MFMA B-fragment order
//          where U_eff = U + fcW^T (x) Wy  (rank-1 fold of the y_prev@Wy recurrence term)
//   prept: H -> per-b LDS-tiled transpose HT[b][d][s] (bf16)
//   k_att:  FUSED per-b: T1 = tanh(H_b@Wa+ba); beta = softmax(T1@Va) (in-register,
//           wave-parallel); pool_b = beta@H_b. poolT layout [b][t][d].
//   k_gx:   Gx = pool @ W + bias + fc_b*Wy (+ (y0-fc_b)*Wy at t==0),
//           packed [g256][t][w8][lane64][gate4] bf16 (8B/lane)
//   k_seq:  256 blocks x 2 batch rows (M=2 in an M=16 MFMA; rows 2-15 zero via a
//           shared zero row -> 3-row slots). Post-MFMA wave-local padded-LDS exchange
//           (stride-18 rows, conflict-free) gives every lane 1 h-value of cell math.
//           U residency: kc0-2,5,6 in VGPRs, kc3-4 in LDS, kc7 streamed (same 64KB for
//           all blocks -> L2-resident).
//           Per-step barrier is lgkmcnt-only (s_barrier), so delayed global h stores
//           and prefetches float across steps.

using bf16x8 = __attribute__((ext_vector_type(8))) short;
using f32x4  = __attribute__((ext_vector_type(4))) float;
using f32x2  = __attribute__((ext_vector_type(2))) float;
using u16x4  = __attribute__((ext_vector_type(4))) unsigned short;

#define DEV static __device__ __forceinline__

DEV unsigned short f2bf(float x) {
    unsigned u = __float_as_uint(x);
    u += 0x7fffu + ((u >> 16) & 1u);          // round-to-nearest-even
    return (unsigned short)(u >> 16);
}
DEV float bf2f(unsigned short s) { return __uint_as_float(((unsigned)s) << 16); }
DEV float sigm(float x) { return 1.0f / (1.0f + __expf(-x)); }
DEV float tanh_f(float x) { float e = __expf(2.0f * x); return 1.0f - 2.0f / (e + 1.0f); }
DEV f32x4 mfma16(bf16x8 a, bf16x8 b, f32x4 c) {
    return __builtin_amdgcn_mfma_f32_16x16x32_bf16(a, b, c, 0, 0, 0);
}

// stage rows x 128 bf16 (row stride 128) into LDS with padded stride 136
DEV void stage128(const unsigned short* __restrict__ src, unsigned short* dst, int rows, int tid) {
    int chunks = rows * 16;
    for (int i = tid; i < chunks; i += 256) {
        int r = i >> 4, c = (i & 15) << 3;
        *(bf16x8*)(dst + r * 136 + c) = *(const bf16x8*)(src + r * 128 + c);
    }
}
// stage rows x 128 f32 -> bf16 LDS (stride 136)
DEV void stage128f(const float* __restrict__ src, unsigned short* dst, int rows, int tid) {
    int chunks = rows * 16;
    for (int i = tid; i < chunks; i += 256) {
        int r = i >> 4, c = (i & 15) << 3;
        const float* s = src + r * 128 + c;
        bf16x8 o;
        #pragma unroll
        for (int e = 0; e < 8; ++e) o[e] = (short)f2bf(s[e]);
        *(bf16x8*)(dst + r * 136 + c) = o;
    }
}

// ---------------- prep kernels ----------------
__global__ void k_prepw(const float* __restrict__ Wa, const float* __restrict__ Va,
                        const float* __restrict__ W, const float* __restrict__ U,
                        const float* __restrict__ fcW, const float* __restrict__ Wy,
                        unsigned short* __restrict__ WaT, unsigned short* __restrict__ VaT,
                        unsigned short* __restrict__ WT, unsigned short* __restrict__ Upk) {
    int idx = blockIdx.x * 256 + threadIdx.x;
    if (idx < 16384) {
        int n = idx >> 7, k = idx & 127;
        WaT[idx] = f2bf(Wa[k * 128 + n]);
    } else if (idx < 32768) {
        int i = idx - 16384;
        int n = i >> 7, k = i & 127;
        VaT[i] = f2bf(Va[k * 128 + n]);
    } else if (idx < 163840) {
        int i = idx - 32768;
        int n = i >> 7, k = i & 127;
        WT[i] = f2bf(W[k * 1024 + n]);
    } else if (idx < 425984) {
        int i = idx - 163840;   // layout: ((((w*8+kc)*8+tt)*64+l)*8+j
        int j = i & 7, ll = (i >> 3) & 63, tt = (i >> 9) & 7, kc = (i >> 12) & 7, w = i >> 15;
        int k = kc * 32 + (ll >> 4) * 8 + j;
        int n = (tt >> 1) * 256 + w * 32 + (tt & 1) * 16 + (ll & 15);
        // rank-1 fold: U_eff = U + fcW^T Wy
        Upk[i] = f2bf(U[k * 1024 + n] + fcW[k] * Wy[n]);
    }
}

// per-b LDS-tiled transpose: HT[b][d][s] (bf16)
__global__ __launch_bounds__(256) void k_prept(const float* __restrict__ H,
                                               unsigned short* __restrict__ HT) {
    __shared__ unsigned short tl[128 * 130];
    int b = blockIdx.x, tid = threadIdx.x;
    const float* Hb = H + (size_t)b * 16384;
    for (int i = tid; i < 16384; i += 256) {
        int s = i >> 7, d = i & 127;
        tl[s * 130 + d] = f2bf(Hb[i]);
    }
    __syncthreads();
    unsigned short* HTb = HT + (size_t)b * 16384;
    for (int i = tid; i < 16384; i += 256) {
        int d = i >> 7, s = i & 127;
        HTb[i] = tl[s * 130 + d];
    }
}

// ---------------- FUSED attention: T1 -> softmax -> pool, one block per b ----------------
__global__ __launch_bounds__(256) void k_att(const float* __restrict__ H,
                                             const unsigned short* __restrict__ WaT,
                                             const unsigned short* __restrict__ VaT,
                                             const unsigned short* __restrict__ HT,
                                             const float* __restrict__ ba,
                                             unsigned short* __restrict__ poolT) {
    __shared__ unsigned short A1[128 * 136];
    __shared__ unsigned short B1[128 * 136];
    int tid = threadIdx.x, b = blockIdx.x;
    int w = tid >> 6, l = tid & 63, q = l >> 4, r = l & 15;

    // phase 1: T1 = tanh(H_b @ WaT + ba)
    stage128f(H + (size_t)b * 16384, A1, 128, tid);
    stage128(WaT, B1, 128, tid);
    __syncthreads();
    f32x4 acc[2][8] = {};
    #pragma unroll
    for (int kc = 0; kc < 4; ++kc)
        #pragma unroll
        for (int mt = 0; mt < 2; ++mt) {
            bf16x8 a = *(const bf16x8*)(A1 + (w * 32 + mt * 16 + r) * 136 + kc * 32 + q * 8);
            #pragma unroll
            for (int nt = 0; nt < 8; ++nt) {
                bf16x8 bb = *(const bf16x8*)(B1 + (nt * 16 + r) * 136 + kc * 32 + q * 8);
                acc[mt][nt] = mfma16(a, bb, acc[mt][nt]);
            }
        }
    __syncthreads();
    // T1 -> B1 (bf16, A-layout); VaT -> A1
    #pragma unroll
    for (int nt = 0; nt < 8; ++nt) {
        float bav = ba[nt * 16 + r];
        #pragma unroll
        for (int mt = 0; mt < 2; ++mt)
            #pragma unroll
            for (int j = 0; j < 4; ++j)
                B1[(w * 32 + mt * 16 + q * 4 + j) * 136 + nt * 16 + r] =
                    f2bf(tanh_f(acc[mt][nt][j] + bav));
    }
    stage128(VaT, A1, 128, tid);
    __syncthreads();

    // phase 2: logits = T1 @ VaT, softmax in-register
    f32x4 lacc[2][8] = {};
    #pragma unroll
    for (int kc = 0; kc < 4; ++kc)
        #pragma unroll
        for (int mt = 0; mt < 2; ++mt) {
            bf16x8 a = *(const bf16x8*)(B1 + (w * 32 + mt * 16 + r) * 136 + kc * 32 + q * 8);
            #pragma unroll
            for (int nt = 0; nt < 8; ++nt) {
                bf16x8 bb = *(const bf16x8*)(A1 + (nt * 16 + r) * 136 + kc * 32 + q * 8);
                lacc[mt][nt] = mfma16(a, bb, lacc[mt][nt]);
            }
        }
    float inv_[2][4];
    #pragma unroll
    for (int mt = 0; mt < 2; ++mt)
        #pragma unroll
        for (int j = 0; j < 4; ++j) {
            float mx = lacc[mt][0][j];
            #pragma unroll
            for (int nt = 1; nt < 8; ++nt) mx = fmaxf(mx, lacc[mt][nt][j]);
            mx = fmaxf(mx, __shfl_xor(mx, 1));
            mx = fmaxf(mx, __shfl_xor(mx, 2));
            mx = fmaxf(mx, __shfl_xor(mx, 4));
            mx = fmaxf(mx, __shfl_xor(mx, 8));
            float s = 0.f;
            #pragma unroll
            for (int nt = 0; nt < 8; ++nt) {
                float e = __expf(lacc[mt][nt][j] - mx);
                lacc[mt][nt][j] = e;
                s += e;
            }
            s += __shfl_xor(s, 1);
            s += __shfl_xor(s, 2);
            s += __shfl_xor(s, 4);
            s += __shfl_xor(s, 8);
            inv_[mt][j] = 1.0f / s;
        }
    __syncthreads();
    // beta -> B1; HT_b -> A1
    #pragma unroll
    for (int mt = 0; mt < 2; ++mt)
        #pragma unroll
        for (int nt = 0; nt < 8; ++nt)
            #pragma unroll
            for (int j = 0; j < 4; ++j)
                B1[(w * 32 + mt * 16 + q * 4 + j) * 136 + nt * 16 + r] =
                    f2bf(lacc[mt][nt][j] * inv_[mt][j]);
    stage128(HT + (size_t)b * 16384, A1, 128, tid);
    __syncthreads();

    // phase 3: pool = beta @ HT_b -> poolT[b][t][d]
    f32x4 pacc[2][8] = {};
    #pragma unroll
    for (int kc = 0; kc < 4; ++kc)
        #pragma unroll
        for (int mt = 0; mt < 2; ++mt) {
            bf16x8 a = *(const bf16x8*)(B1 + (w * 32 + mt * 16 + r) * 136 + kc * 32 + q * 8);
            #pragma unroll
            for (int nt = 0; nt < 8; ++nt) {
                bf16x8 bb = *(const bf16x8*)(A1 + (nt * 16 + r) * 136 + kc * 32 + q * 8);
                pacc[mt][nt] = mfma16(a, bb, pacc[mt][nt]);
            }
        }
    unsigned short* pb = poolT + (size_t)b * 16384;
    #pragma unroll
    for (int mt = 0; mt < 2; ++mt)
        #pragma unroll
        for (int nt = 0; nt < 8; ++nt)
            #pragma unroll
            for (int j = 0; j < 4; ++j)
                pb[(w * 32 + mt * 16 + q * 4 + j) * 128 + nt * 16 + r] = f2bf(pacc[mt][nt][j]);
}

// ---------------- Gx = pool @ W + bias + y-term, packed [g256][t][w8][l64][gate4] ----------------
__global__ __launch_bounds__(256) void k_gx(const unsigned short* __restrict__ poolT,
                                            const unsigned short* __restrict__ WT,
                                            const float* __restrict__ bias,
                                            const float* __restrict__ Wy,
                                            const float* __restrict__ y0,
                                            const float* __restrict__ fcb,
                                            unsigned short* __restrict__ Gxp) {
    __shared__ unsigned short a_lds[64 * 136];
    __shared__ unsigned short b_lds[128 * 136];
    int tid = threadIdx.x;
    int mblk = blockIdx.x >> 3, nb = blockIdx.x & 7;
    int b = mblk >> 1, t0 = (mblk & 1) * 64, n0 = nb * 128;
    stage128(poolT + (size_t)b * 16384 + t0 * 128, a_lds, 64, tid);
    stage128(WT + (size_t)n0 * 128, b_lds, 128, tid);
    __syncthreads();
    int w = tid >> 6, l = tid & 63, q = l >> 4, r = l & 15;
    f32x4 acc[8] = {};
    #pragma unroll
    for (int kc = 0; kc < 4; ++kc) {
        bf16x8 a = *(const bf16x8*)(a_lds + (w * 16 + r) * 136 + kc * 32 + q * 8);
        #pragma unroll
        for (int nt = 0; nt < 8; ++nt) {
            bf16x8 bb = *(const bf16x8*)(b_lds + (nt * 16 + r) * 136 + kc * 32 + q * 8);
            acc[nt] = mfma16(a, bb, acc[nt]);
        }
    }
    int g = b >> 1, rowbit = b & 1;
    float fcb0 = fcb[0];
    float y00 = y0[b];
    #pragma unroll
    for (int nt = 0; nt < 8; ++nt) {
        int col = n0 + nt * 16 + r;
        float bv = bias[col], wv = Wy[col];
        int c = col & 255;
        int w_s = c >> 5, ch = (c >> 4) & 1, r_s = c & 15;
        int gate = col >> 8;
        int l_s = (ch * 2 + rowbit) * 16 + r_s;
        size_t base = ((((size_t)g * 128) * 8 + w_s) * 64 + l_s) * 4 + gate;
        #pragma unroll
        for (int j = 0; j < 4; ++j) {
            int t = t0 + w * 16 + q * 4 + j;
            float yb = (t == 0) ? y00 : fcb0;
            Gxp[base + (size_t)t * 2048] = f2bf(acc[nt][j] + bv + yb * wv);
        }
    }
}

// ---------------- sequential LSTM: 256 blocks x 2 batch rows ----------------
// dynbuf: U kc3-4 (131072) | h 3-row-slot dbuf (3072) | scr pad-18 (9216) | ypart (64)
__global__ __launch_bounds__(512, 2) void k_seq(const unsigned short* __restrict__ Gxp,
                                                const unsigned short* __restrict__ Upk,
                                                const float* __restrict__ fcW,
                                                const float* __restrict__ fcb,
                                                float* __restrict__ out) {
    extern __shared__ __align__(16) char dynbuf[];
    unsigned short* u2   = (unsigned short*)dynbuf;             // 65536 shorts (kc3,4)
    unsigned short* h_fl = (unsigned short*)(dynbuf + 131072);  // 2 x 768 shorts
    float* scr           = (float*)(dynbuf + 134144);           // [8w][16r][18] pad-18
    float* ypart         = (float*)(dynbuf + 143360);           // [8w][2row]

    int tid = threadIdx.x;
    int g = blockIdx.x;                 // batch group of 2 rows
    int w = tid >> 6, l = tid & 63, q = l >> 4, r = l & 15;
    int row = q & 1, ch = q >> 1;       // this lane's h: batch row, column half
    int rr = (r < 2) ? r : 2;           // A-frag row; 2 = shared zero row
    float fc_b0 = fcb[0];

    // register-resident U_eff: kc 0,1,2,5,6
    bf16x8 u_res[5][8];
    {
        const bf16x8* up = (const bf16x8*)Upk;
        const int kcs[5] = {0, 1, 2, 5, 6};
        #pragma unroll
        for (int i = 0; i < 5; ++i)
            #pragma unroll
            for (int tt = 0; tt < 8; ++tt)
                u_res[i][tt] = up[((w * 8 + kcs[i]) * 8 + tt) * 64 + l];
    }
    // LDS-resident U_eff: kc 3..4
    #pragma unroll
    for (int kcL = 0; kcL < 2; ++kcL)
        #pragma unroll
        for (int tt = 0; tt < 8; ++tt) {
            size_t gofs = (size_t)(((w * 8 + 3 + kcL) * 8 + tt) * 64 + l) * 8;
            size_t lofs = (size_t)(((w * 2 + kcL) * 8 + tt) * 64 + l) * 8;
            *(bf16x8*)(u2 + lofs) = *(const bf16x8*)(Upk + gofs);
        }

    float fw0 = fcW[w * 32 + ch * 16 + r];
    float c_st = 0.f, hv_st = 0.f;

    for (int i = tid; i < 1536; i += 512) h_fl[i] = 0;   // h(0)=0, zero rows stay zero
    __syncthreads();

    // per-lane pointers
    const unsigned short* gxp = Gxp + ((((size_t)g * 128 * 8 + w) * 64 + l) * 4); // +2048/t
    const bf16x8* u7p = (const bf16x8*)Upk + (w * 8 + 7) * 512 + l;               // kc7 stream
    float* outp = out + 512 + (size_t)(g * 2 + row) * 32768 + w * 32 + ch * 16 + r;
    float* scw = scr + (w * 16 + r) * 18;   // exchange row (source lane r of this wave)
    const float* scrd = scw + 2 * ch + row;

    for (int t = 0; t < 128; ++t) {
        unsigned short* hp = h_fl + (t & 1) * 768;
        unsigned short* hn = h_fl + ((t & 1) ^ 1) * 768;

        // ---- delayed global store of previous step's h (floats across barriers) ----
        if (t > 0) {
            *outp = hv_st;
            outp += 256;
        }

        // ---- streamed U kc7: issued at step top, consumed last ----
        bf16x8 u7[8];
        #pragma unroll
        for (int tt = 0; tt < 8; ++tt) u7[tt] = u7p[tt * 64];

        // ---- Gx prefetch: 4 gates x bf16 (8B) ----
        u16x4 gxv = *(const u16x4*)gxp;

        // ---- MFMA: gates partial = h_prev @ U_eff ----
        f32x4 acc[8] = {};
        #pragma unroll
        for (int i = 0; i < 3; ++i) {          // reg kc 0..2
            bf16x8 a = *(const bf16x8*)(hp + ((i * 4 + q) * 3 + rr) * 8);
            #pragma unroll
            for (int tt = 0; tt < 8; ++tt) acc[tt] = mfma16(a, u_res[i][tt], acc[tt]);
        }
        #pragma unroll
        for (int kcL = 0; kcL < 2; ++kcL) {    // LDS kc 3..4
            bf16x8 a = *(const bf16x8*)(hp + (((3 + kcL) * 4 + q) * 3 + rr) * 8);
            #pragma unroll
            for (int tt = 0; tt < 8; ++tt) {
                bf16x8 u = *(const bf16x8*)(u2 + (size_t)(((w * 2 + kcL) * 8 + tt) * 64 + l) * 8);
                acc[tt] = mfma16(a, u, acc[tt]);
            }
        }
        #pragma unroll
        for (int i = 0; i < 2; ++i) {          // reg kc 5..6
            bf16x8 a = *(const bf16x8*)(hp + (((5 + i) * 4 + q) * 3 + rr) * 8);
            #pragma unroll
            for (int tt = 0; tt < 8; ++tt) acc[tt] = mfma16(a, u_res[3 + i][tt], acc[tt]);
        }
        {                                      // streamed kc7
            bf16x8 a = *(const bf16x8*)(hp + ((7 * 4 + q) * 3 + rr) * 8);
            #pragma unroll
            for (int tt = 0; tt < 8; ++tt) acc[tt] = mfma16(a, u7[tt], acc[tt]);
        }

        // ---- wave-local exchange: q==0 lanes hold both valid rows (j=0,1) ----
        //      scr row stride 18 floats: r*18 mod 32 covers all even banks ->
        //      b64 writes conflict-free, b32 reads 2-way max.
        if (q == 0) {
            #pragma unroll
            for (int tt = 0; tt < 8; ++tt)
                *(f32x2*)(scw + tt * 2) = f32x2{acc[tt][0], acc[tt][1]};
        }
        asm volatile("s_waitcnt lgkmcnt(0)" ::: "memory");
        __builtin_amdgcn_sched_barrier(0);
        float av[4];
        #pragma unroll
        for (int gp = 0; gp < 4; ++gp) av[gp] = scrd[gp * 4];

        // ---- LSTM cell: 1 value/lane, row=q&1, col=w*32+(q>>1)*16+r ----
        {
            float iv = sigm(av[0] + bf2f(gxv[0]));
            float fv = sigm(av[1] + bf2f(gxv[1]));
            float gv = tanh_f(av[2] + bf2f(gxv[2]));
            float ov = sigm(av[3] + bf2f(gxv[3]));
            float c = fv * c_st + iv * gv;
            c_st = c;
            float hv = ov * tanh_f(c);
            // h write in A-fragment order: slot = kc(w)*4 + qd, 3-row slots
            hn[((w * 4 + ch * 2 + (r >> 3)) * 3 + row) * 8 + (r & 7)] = f2bf(hv);
            hv_st = hv;
            if (t == 127) {   // final y = fc(h_127) + fc_b, exact f32 path
                float v = hv * fw0;
                v += __shfl_xor(v, 1);
                v += __shfl_xor(v, 2);
                v += __shfl_xor(v, 4);
                v += __shfl_xor(v, 8);
                v += __shfl_xor(v, 32);        // combine column halves (same row)
                if (r == 0 && ch == 0) ypart[w * 2 + row] = v;
            }
        }
        gxp += 2048;
        // ---- lgkm-only barrier: h LDS visibility without vmcnt drain ----
        asm volatile("s_waitcnt lgkmcnt(0)\n\ts_barrier" ::: "memory");
    }

    // final step's h store
    *outp = hv_st;

    __syncthreads();
    if (tid < 2) {
        float y = fc_b0;
        #pragma unroll
        for (int ww = 0; ww < 8; ++ww) y += ypart[ww * 2 + tid];
        out[g * 2 + tid] = y;
    }
}

extern "C" void kernel_launch(void* const* d_in, const int* in_sizes, int n_in,
                              void* d_out, int out_size, void* d_ws, size_t ws_size,
                              hipStream_t stream) {
    const float* H    = (const float*)d_in[0];
    const float* y0   = (const float*)d_in[1];
    const float* Wa   = (const float*)d_in[2];
    // d_in[3] = Ua: multiplied by an all-zero state in the reference -> unused
    const float* ba   = (const float*)d_in[4];
    const float* Va   = (const float*)d_in[5];
    const float* W    = (const float*)d_in[6];
    const float* U    = (const float*)d_in[7];
    const float* bias = (const float*)d_in[8];
    const float* Wy   = (const float*)d_in[9];
    const float* fcW  = (const float*)d_in[10];
    const float* fcb  = (const float*)d_in[11];
    float* out = (float*)d_out;
    char* ws = (char*)d_ws;

    unsigned short* HT    = (unsigned short*)(ws);                      // 16.8 MB
    unsigned short* poolT = (unsigned short*)(ws + 16777216);           // 16.8 MB, [b][t][d]
    unsigned short* Gxp   = (unsigned short*)(ws + 2 * 16777216);       // 134.2 MB
    unsigned short* WaT   = (unsigned short*)(ws + 2 * 16777216 + 134217728);
    unsigned short* VaT   = WaT + 16384;
    unsigned short* WT    = VaT + 16384;
    unsigned short* Upk   = WT + 131072;

    hipFuncSetAttribute((const void*)k_seq, hipFuncAttributeMaxDynamicSharedMemorySize, 143424);

    hipLaunchKernelGGL(k_prepw, dim3(1664), dim3(256), 0, stream, Wa, Va, W, U, fcW, Wy,
                       WaT, VaT, WT, Upk);
    hipLaunchKernelGGL(k_prept, dim3(512), dim3(256), 0, stream, H, HT);
    hipLaunchKernelGGL(k_att, dim3(512), dim3(256), 0, stream, H, WaT, VaT, HT, ba, poolT);
    hipLaunchKernelGGL(k_gx, dim3(8192), dim3(256), 0, stream, poolT, WT, bias, Wy, y0, fcb, Gxp);
    hipLaunchKernelGGL(k_seq, dim3(256), dim3(512), 143424, stream, Gxp, Upk, fcW, fcb, out);
}

// Round 5
// 573.135 us; speedup vs baseline: 1.0049x; 1.0049x over previous
//
#include <hip/hip_runtime.h>
#include <hip/hip_bf16.h>

// Shapes: B=512, S=128, D=128, HS=256, 4HS=1024, O=1.
// Pipeline (all bf16 MFMA, f32 accum):
//   prepw: WaT/VaT/WT transposed bf16 weights + U_eff packed into MFMA B-fragment order
//          where U_eff = U + fcW^T (x) Wy  (rank-1 fold of the y_prev@Wy recurrence term)
//   prept: H -> per-b LDS-tiled transpose HT[b][d][s] (bf16)
//   k_att:  FUSED per-b: T1 = tanh(H_b@Wa+ba); beta = softmax(T1@Va); pool = beta@H_b.
//   k_gx:   Gx = pool @ W + bias + fc_b*Wy (+ (y0-fc_b)*Wy at t==0),
//           packed [g256][t128][ws8][r16][j2][nt8] bf16 -> 16B-contiguous stores, and
//           32B-contiguous reads for k_seq's q==0 lanes.
//   k_seq:  256 blocks x 2 batch rows. waves_per_eu(2,2) pins the 256-VGPR budget so
//           U_eff kc{0,1,2,5,6,7} is TRULY register-resident (192 VGPRs); kc3-4 in LDS.
//           Steady-state VMEM = 32B Gx read (q==0 lanes) + 4B out store per lane.
//           Post-MFMA wave-local padded-LDS exchange (stride-18, conflict-free) gives
//           every lane 1 h-value of cell math. Per-step barrier is lgkmcnt-only.

using bf16x8 = __attribute__((ext_vector_type(8))) short;
using f32x4  = __attribute__((ext_vector_type(4))) float;
using f32x2  = __attribute__((ext_vector_type(2))) float;

#define DEV static __device__ __forceinline__

DEV unsigned short f2bf(float x) {
    unsigned u = __float_as_uint(x);
    u += 0x7fffu + ((u >> 16) & 1u);          // round-to-nearest-even
    return (unsigned short)(u >> 16);
}
DEV float bf2f(unsigned short s) { return __uint_as_float(((unsigned)s) << 16); }
DEV float sigm(float x) { return 1.0f / (1.0f + __expf(-x)); }
DEV float tanh_f(float x) { float e = __expf(2.0f * x); return 1.0f - 2.0f / (e + 1.0f); }
DEV f32x4 mfma16(bf16x8 a, bf16x8 b, f32x4 c) {
    return __builtin_amdgcn_mfma_f32_16x16x32_bf16(a, b, c, 0, 0, 0);
}

// stage rows x 128 bf16 (row stride 128) into LDS with padded stride 136
DEV void stage128(const unsigned short* __restrict__ src, unsigned short* dst, int rows, int tid) {
    int chunks = rows * 16;
    for (int i = tid; i < chunks; i += 256) {
        int r = i >> 4, c = (i & 15) << 3;
        *(bf16x8*)(dst + r * 136 + c) = *(const bf16x8*)(src + r * 128 + c);
    }
}
// stage rows x 128 f32 -> bf16 LDS (stride 136)
DEV void stage128f(const float* __restrict__ src, unsigned short* dst, int rows, int tid) {
    int chunks = rows * 16;
    for (int i = tid; i < chunks; i += 256) {
        int r = i >> 4, c = (i & 15) << 3;
        const float* s = src + r * 128 + c;
        bf16x8 o;
        #pragma unroll
        for (int e = 0; e < 8; ++e) o[e] = (short)f2bf(s[e]);
        *(bf16x8*)(dst + r * 136 + c) = o;
    }
}

// ---------------- prep kernels ----------------
__global__ void k_prepw(const float* __restrict__ Wa, const float* __restrict__ Va,
                        const float* __restrict__ W, const float* __restrict__ U,
                        const float* __restrict__ fcW, const float* __restrict__ Wy,
                        unsigned short* __restrict__ WaT, unsigned short* __restrict__ VaT,
                        unsigned short* __restrict__ WT, unsigned short* __restrict__ Upk) {
    int idx = blockIdx.x * 256 + threadIdx.x;
    if (idx < 16384) {
        int n = idx >> 7, k = idx & 127;
        WaT[idx] = f2bf(Wa[k * 128 + n]);
    } else if (idx < 32768) {
        int i = idx - 16384;
        int n = i >> 7, k = i & 127;
        VaT[i] = f2bf(Va[k * 128 + n]);
    } else if (idx < 163840) {
        int i = idx - 32768;
        int n = i >> 7, k = i & 127;
        WT[i] = f2bf(W[k * 1024 + n]);
    } else if (idx < 425984) {
        int i = idx - 163840;   // layout: ((((w*8+kc)*8+tt)*64+l)*8+j
        int j = i & 7, ll = (i >> 3) & 63, tt = (i >> 9) & 7, kc = (i >> 12) & 7, w = i >> 15;
        int k = kc * 32 + (ll >> 4) * 8 + j;
        int n = (tt >> 1) * 256 + w * 32 + (tt & 1) * 16 + (ll & 15);
        // rank-1 fold: U_eff = U + fcW^T Wy
        Upk[i] = f2bf(U[k * 1024 + n] + fcW[k] * Wy[n]);
    }
}

// per-b LDS-tiled transpose: HT[b][d][s] (bf16)
__global__ __launch_bounds__(256) void k_prept(const float* __restrict__ H,
                                               unsigned short* __restrict__ HT) {
    __shared__ unsigned short tl[128 * 130];
    int b = blockIdx.x, tid = threadIdx.x;
    const float* Hb = H + (size_t)b * 16384;
    for (int i = tid; i < 16384; i += 256) {
        int s = i >> 7, d = i & 127;
        tl[s * 130 + d] = f2bf(Hb[i]);
    }
    __syncthreads();
    unsigned short* HTb = HT + (size_t)b * 16384;
    for (int i = tid; i < 16384; i += 256) {
        int d = i >> 7, s = i & 127;
        HTb[i] = tl[s * 130 + d];
    }
}

// ---------------- FUSED attention: T1 -> softmax -> pool, one block per b ----------------
__global__ __launch_bounds__(256) void k_att(const float* __restrict__ H,
                                             const unsigned short* __restrict__ WaT,
                                             const unsigned short* __restrict__ VaT,
                                             const unsigned short* __restrict__ HT,
                                             const float* __restrict__ ba,
                                             unsigned short* __restrict__ poolT) {
    __shared__ unsigned short A1[128 * 136];
    __shared__ unsigned short B1[128 * 136];
    int tid = threadIdx.x, b = blockIdx.x;
    int w = tid >> 6, l = tid & 63, q = l >> 4, r = l & 15;

    // phase 1: T1 = tanh(H_b @ WaT + ba)
    stage128f(H + (size_t)b * 16384, A1, 128, tid);
    stage128(WaT, B1, 128, tid);
    __syncthreads();
    f32x4 acc[2][8] = {};
    #pragma unroll
    for (int kc = 0; kc < 4; ++kc)
        #pragma unroll
        for (int mt = 0; mt < 2; ++mt) {
            bf16x8 a = *(const bf16x8*)(A1 + (w * 32 + mt * 16 + r) * 136 + kc * 32 + q * 8);
            #pragma unroll
            for (int nt = 0; nt < 8; ++nt) {
                bf16x8 bb = *(const bf16x8*)(B1 + (nt * 16 + r) * 136 + kc * 32 + q * 8);
                acc[mt][nt] = mfma16(a, bb, acc[mt][nt]);
            }
        }
    __syncthreads();
    // T1 -> B1 (bf16, A-layout); VaT -> A1
    #pragma unroll
    for (int nt = 0; nt < 8; ++nt) {
        float bav = ba[nt * 16 + r];
        #pragma unroll
        for (int mt = 0; mt < 2; ++mt)
            #pragma unroll
            for (int j = 0; j < 4; ++j)
                B1[(w * 32 + mt * 16 + q * 4 + j) * 136 + nt * 16 + r] =
                    f2bf(tanh_f(acc[mt][nt][j] + bav));
    }
    stage128(VaT, A1, 128, tid);
    __syncthreads();

    // phase 2: logits = T1 @ VaT, softmax in-register
    f32x4 lacc[2][8] = {};
    #pragma unroll
    for (int kc = 0; kc < 4; ++kc)
        #pragma unroll
        for (int mt = 0; mt < 2; ++mt) {
            bf16x8 a = *(const bf16x8*)(B1 + (w * 32 + mt * 16 + r) * 136 + kc * 32 + q * 8);
            #pragma unroll
            for (int nt = 0; nt < 8; ++nt) {
                bf16x8 bb = *(const bf16x8*)(A1 + (nt * 16 + r) * 136 + kc * 32 + q * 8);
                lacc[mt][nt] = mfma16(a, bb, lacc[mt][nt]);
            }
        }
    float inv_[2][4];
    #pragma unroll
    for (int mt = 0; mt < 2; ++mt)
        #pragma unroll
        for (int j = 0; j < 4; ++j) {
            float mx = lacc[mt][0][j];
            #pragma unroll
            for (int nt = 1; nt < 8; ++nt) mx = fmaxf(mx, lacc[mt][nt][j]);
            mx = fmaxf(mx, __shfl_xor(mx, 1));
            mx = fmaxf(mx, __shfl_xor(mx, 2));
            mx = fmaxf(mx, __shfl_xor(mx, 4));
            mx = fmaxf(mx, __shfl_xor(mx, 8));
            float s = 0.f;
            #pragma unroll
            for (int nt = 0; nt < 8; ++nt) {
                float e = __expf(lacc[mt][nt][j] - mx);
                lacc[mt][nt][j] = e;
                s += e;
            }
            s += __shfl_xor(s, 1);
            s += __shfl_xor(s, 2);
            s += __shfl_xor(s, 4);
            s += __shfl_xor(s, 8);
            inv_[mt][j] = 1.0f / s;
        }
    __syncthreads();
    // beta -> B1; HT_b -> A1
    #pragma unroll
    for (int mt = 0; mt < 2; ++mt)
        #pragma unroll
        for (int nt = 0; nt < 8; ++nt)
            #pragma unroll
            for (int j = 0; j < 4; ++j)
                B1[(w * 32 + mt * 16 + q * 4 + j) * 136 + nt * 16 + r] =
                    f2bf(lacc[mt][nt][j] * inv_[mt][j]);
    stage128(HT + (size_t)b * 16384, A1, 128, tid);
    __syncthreads();

    // phase 3: pool = beta @ HT_b -> poolT[b][t][d]
    f32x4 pacc[2][8] = {};
    #pragma unroll
    for (int kc = 0; kc < 4; ++kc)
        #pragma unroll
        for (int mt = 0; mt < 2; ++mt) {
            bf16x8 a = *(const bf16x8*)(B1 + (w * 32 + mt * 16 + r) * 136 + kc * 32 + q * 8);
            #pragma unroll
            for (int nt = 0; nt < 8; ++nt) {
                bf16x8 bb = *(const bf16x8*)(A1 + (nt * 16 + r) * 136 + kc * 32 + q * 8);
                pacc[mt][nt] = mfma16(a, bb, pacc[mt][nt]);
            }
        }
    unsigned short* pb = poolT + (size_t)b * 16384;
    #pragma unroll
    for (int mt = 0; mt < 2; ++mt)
        #pragma unroll
        for (int nt = 0; nt < 8; ++nt)
            #pragma unroll
            for (int j = 0; j < 4; ++j)
                pb[(w * 32 + mt * 16 + q * 4 + j) * 128 + nt * 16 + r] = f2bf(pacc[mt][nt][j]);
}

// ---------------- Gx = pool @ W + bias + y-term ----------------
// block = (b, t-half, ws col-group): computes all 4 gates of a 32-col slice.
// Gxp layout: ((((g*128 + t)*8 + ws)*16 + r)*16 + jb*8 + nt  -> 16B stores, 32B k_seq reads.
__global__ __launch_bounds__(256) void k_gx(const unsigned short* __restrict__ poolT,
                                            const unsigned short* __restrict__ WT,
                                            const float* __restrict__ bias,
                                            const float* __restrict__ Wy,
                                            const float* __restrict__ y0,
                                            const float* __restrict__ fcb,
                                            unsigned short* __restrict__ Gxp) {
    __shared__ unsigned short a_lds[64 * 136];
    __shared__ unsigned short b_lds[128 * 136];
    int tid = threadIdx.x;
    int b = blockIdx.x >> 4;
    int thalf = (blockIdx.x >> 3) & 1;
    int ws = blockIdx.x & 7;
    stage128(poolT + (size_t)b * 16384 + thalf * 64 * 128, a_lds, 64, tid);
    #pragma unroll
    for (int gate = 0; gate < 4; ++gate)
        stage128(WT + (size_t)(gate * 256 + ws * 32) * 128, b_lds + gate * 32 * 136, 32, tid);
    __syncthreads();
    int w = tid >> 6, l = tid & 63, q = l >> 4, r = l & 15;
    f32x4 acc[8] = {};
    #pragma unroll
    for (int kc = 0; kc < 4; ++kc) {
        bf16x8 a = *(const bf16x8*)(a_lds + (w * 16 + r) * 136 + kc * 32 + q * 8);
        #pragma unroll
        for (int nt = 0; nt < 8; ++nt) {
            bf16x8 bb = *(const bf16x8*)(b_lds + (nt * 16 + r) * 136 + kc * 32 + q * 8);
            acc[nt] = mfma16(a, bb, acc[nt]);
        }
    }
    int g = b >> 1, jb = b & 1;
    float fcb0 = fcb[0], y00 = y0[b];
    float bv[8], wv[8];
    #pragma unroll
    for (int nt = 0; nt < 8; ++nt) {
        int col = (nt >> 1) * 256 + ws * 32 + (nt & 1) * 16 + r;
        bv[nt] = bias[col];
        wv[nt] = Wy[col];
    }
    #pragma unroll
    for (int j = 0; j < 4; ++j) {
        int t = thalf * 64 + w * 16 + q * 4 + j;
        float yb = (t == 0) ? y00 : fcb0;
        bf16x8 o;
        #pragma unroll
        for (int nt = 0; nt < 8; ++nt)
            o[nt] = (short)f2bf(acc[nt][j] + bv[nt] + yb * wv[nt]);
        size_t addr = ((((size_t)g * 128 + t) * 8 + ws) * 16 + r) * 16 + jb * 8;
        *(bf16x8*)(Gxp + addr) = o;   // 16B store, 32B stride across r
    }
}

// ---------------- sequential LSTM: 256 blocks x 2 batch rows ----------------
// dynbuf: U kc3-4 (131072) | h 3-row-slot dbuf (3072) | scr pad-18 (9216) | ypart (64)
__attribute__((amdgpu_waves_per_eu(2, 2)))
__global__ __launch_bounds__(512) void k_seq(const unsigned short* __restrict__ Gxp,
                                             const unsigned short* __restrict__ Upk,
                                             const float* __restrict__ fcW,
                                             const float* __restrict__ fcb,
                                             float* __restrict__ out) {
    extern __shared__ __align__(16) char dynbuf[];
    unsigned short* u2   = (unsigned short*)dynbuf;             // 65536 shorts (kc3,4)
    unsigned short* h_fl = (unsigned short*)(dynbuf + 131072);  // 2 x 768 shorts
    float* scr           = (float*)(dynbuf + 134144);           // [8w][16r][18] pad-18
    float* ypart         = (float*)(dynbuf + 143360);           // [8w][2row]

    int tid = threadIdx.x;
    int g = blockIdx.x;                 // batch group of 2 rows
    int w = tid >> 6, l = tid & 63, q = l >> 4, r = l & 15;
    int row = q & 1, ch = q >> 1;       // this lane's h: batch row, column half
    int rr = (r < 2) ? r : 2;           // A-frag row; 2 = shared zero row
    float fc_b0 = fcb[0];

    // register-resident U_eff: kc 0,1,2,5,6,7 (192 VGPRs; waves_per_eu(2,2) -> 256 budget)
    bf16x8 u_res[6][8];
    {
        const bf16x8* up = (const bf16x8*)Upk;
        const int kcs[6] = {0, 1, 2, 5, 6, 7};
        #pragma unroll
        for (int i = 0; i < 6; ++i)
            #pragma unroll
            for (int tt = 0; tt < 8; ++tt)
                u_res[i][tt] = up[((w * 8 + kcs[i]) * 8 + tt) * 64 + l];
    }
    // LDS-resident U_eff: kc 3..4
    #pragma unroll
    for (int kcL = 0; kcL < 2; ++kcL)
        #pragma unroll
        for (int tt = 0; tt < 8; ++tt) {
            size_t gofs = (size_t)(((w * 8 + 3 + kcL) * 8 + tt) * 64 + l) * 8;
            size_t lofs = (size_t)(((w * 2 + kcL) * 8 + tt) * 64 + l) * 8;
            *(bf16x8*)(u2 + lofs) = *(const bf16x8*)(Upk + gofs);
        }

    float fw0 = fcW[w * 32 + ch * 16 + r];
    float c_st = 0.f, hv_st = 0.f;

    for (int i = tid; i < 1536; i += 512) h_fl[i] = 0;   // h(0)=0, zero rows stay zero
    __syncthreads();

    // per-lane pointers
    const unsigned short* gxq = Gxp + (size_t)g * 262144 + w * 256 + r * 16;  // +2048/t
    float* outp = out + 512 + (size_t)(g * 2 + row) * 32768 + w * 32 + ch * 16 + r;
    float* scw = scr + (w * 16 + r) * 18;   // exchange row (source lane r of this wave)
    const float* scrd = scw + 2 * ch + row;

    for (int t = 0; t < 128; ++t) {
        unsigned short* hp = h_fl + (t & 1) * 768;
        unsigned short* hn = h_fl + ((t & 1) ^ 1) * 768;

        // ---- delayed global store of previous step's h (floats across barriers) ----
        if (t > 0) {
            *outp = hv_st;
            outp += 256;
        }

        // ---- Gx prefetch: q==0 lanes read both rows' 8 gate-cols (32B contiguous) ----
        bf16x8 gxa, gxb;
        if (q == 0) {
            gxa = *(const bf16x8*)gxq;
            gxb = *(const bf16x8*)(gxq + 8);
        }

        // ---- MFMA: gates partial = h_prev @ U_eff (all U in regs/LDS, no stream) ----
        f32x4 acc[8] = {};
        #pragma unroll
        for (int i = 0; i < 3; ++i) {          // reg kc 0..2
            bf16x8 a = *(const bf16x8*)(hp + ((i * 4 + q) * 3 + rr) * 8);
            #pragma unroll
            for (int tt = 0; tt < 8; ++tt) acc[tt] = mfma16(a, u_res[i][tt], acc[tt]);
        }
        #pragma unroll
        for (int kcL = 0; kcL < 2; ++kcL) {    // LDS kc 3..4
            bf16x8 a = *(const bf16x8*)(hp + (((3 + kcL) * 4 + q) * 3 + rr) * 8);
            #pragma unroll
            for (int tt = 0; tt < 8; ++tt) {
                bf16x8 u = *(const bf16x8*)(u2 + (size_t)(((w * 2 + kcL) * 8 + tt) * 64 + l) * 8);
                acc[tt] = mfma16(a, u, acc[tt]);
            }
        }
        #pragma unroll
        for (int i = 0; i < 3; ++i) {          // reg kc 5..7
            bf16x8 a = *(const bf16x8*)(hp + (((5 + i) * 4 + q) * 3 + rr) * 8);
            #pragma unroll
            for (int tt = 0; tt < 8; ++tt) acc[tt] = mfma16(a, u_res[3 + i][tt], acc[tt]);
        }

        // ---- add Gx pre-exchange (q==0 lanes own the valid rows) ----
        if (q == 0) {
            #pragma unroll
            for (int tt = 0; tt < 8; ++tt) {
                acc[tt][0] += bf2f((unsigned short)gxa[tt]);
                acc[tt][1] += bf2f((unsigned short)gxb[tt]);
            }
        }

        // ---- wave-local exchange: q==0 lanes hold both valid rows (j=0,1) ----
        if (q == 0) {
            #pragma unroll
            for (int tt = 0; tt < 8; ++tt)
                *(f32x2*)(scw + tt * 2) = f32x2{acc[tt][0], acc[tt][1]};
        }
        asm volatile("s_waitcnt lgkmcnt(0)" ::: "memory");
        __builtin_amdgcn_sched_barrier(0);
        float av[4];
        #pragma unroll
        for (int gp = 0; gp < 4; ++gp) av[gp] = scrd[gp * 4];

        // ---- LSTM cell: 1 value/lane, row=q&1, col=w*32+(q>>1)*16+r ----
        {
            float iv = sigm(av[0]);
            float fv = sigm(av[1]);
            float gv = tanh_f(av[2]);
            float ov = sigm(av[3]);
            float c = fv * c_st + iv * gv;
            c_st = c;
            float hv = ov * tanh_f(c);
            // h write in A-fragment order: slot = kc(w)*4 + qd, 3-row slots
            hn[((w * 4 + ch * 2 + (r >> 3)) * 3 + row) * 8 + (r & 7)] = f2bf(hv);
            hv_st = hv;
            if (t == 127) {   // final y = fc(h_127) + fc_b, exact f32 path
                float v = hv * fw0;
                v += __shfl_xor(v, 1);
                v += __shfl_xor(v, 2);
                v += __shfl_xor(v, 4);
                v += __shfl_xor(v, 8);
                v += __shfl_xor(v, 32);        // combine column halves (same row)
                if (r == 0 && ch == 0) ypart[w * 2 + row] = v;
            }
        }
        gxq += 2048;
        // ---- lgkm-only barrier: h LDS visibility without vmcnt drain ----
        asm volatile("s_waitcnt lgkmcnt(0)\n\ts_barrier" ::: "memory");
    }

    // final step's h store
    *outp = hv_st;

    __syncthreads();
    if (tid < 2) {
        float y = fc_b0;
        #pragma unroll
        for (int ww = 0; ww < 8; ++ww) y += ypart[ww * 2 + tid];
        out[g * 2 + tid] = y;
    }
}

extern "C" void kernel_launch(void* const* d_in, const int* in_sizes, int n_in,
                              void* d_out, int out_size, void* d_ws, size_t ws_size,
                              hipStream_t stream) {
    const float* H    = (const float*)d_in[0];
    const float* y0   = (const float*)d_in[1];
    const float* Wa   = (const float*)d_in[2];
    // d_in[3] = Ua: multiplied by an all-zero state in the reference -> unused
    const float* ba   = (const float*)d_in[4];
    const float* Va   = (const float*)d_in[5];
    const float* W    = (const float*)d_in[6];
    const float* U    = (const float*)d_in[7];
    const float* bias = (const float*)d_in[8];
    const float* Wy   = (const float*)d_in[9];
    const float* fcW  = (const float*)d_in[10];
    const float* fcb  = (const float*)d_in[11];
    float* out = (float*)d_out;
    char* ws = (char*)d_ws;

    unsigned short* HT    = (unsigned short*)(ws);                      // 16.8 MB
    unsigned short* poolT = (unsigned short*)(ws + 16777216);           // 16.8 MB, [b][t][d]
    unsigned short* Gxp   = (unsigned short*)(ws + 2 * 16777216);       // 134.2 MB
    unsigned short* WaT   = (unsigned short*)(ws + 2 * 16777216 + 134217728);
    unsigned short* VaT   = WaT + 16384;
    unsigned short* WT    = VaT + 16384;
    unsigned short* Upk   = WT + 131072;

    hipFuncSetAttribute((const void*)k_seq, hipFuncAttributeMaxDynamicSharedMemorySize, 143424);

    hipLaunchKernelGGL(k_prepw, dim3(1664), dim3(256), 0, stream, Wa, Va, W, U, fcW, Wy,
                       WaT, VaT, WT, Upk);
    hipLaunchKernelGGL(k_prept, dim3(512), dim3(256), 0, stream, H, HT);
    hipLaunchKernelGGL(k_att, dim3(512), dim3(256), 0, stream, H, WaT, VaT, HT, ba, poolT);
    hipLaunchKernelGGL(k_gx, dim3(8192), dim3(256), 0, stream, poolT, WT, bias, Wy, y0, fcb, Gxp);
    hipLaunchKernelGGL(k_seq, dim3(256), dim3(512), 143424, stream, Gxp, Upk, fcW, fcb, out);
}